// Round 14
// baseline (156.839 us; speedup 1.0000x reference)
//
#include <hip/hip_runtime.h>
#include <math.h>

#define NN   40000
#define NP   40064          // padded rows (multiple of 64)
#define EE   320000
#define ET   (EE + NN)      // 360000 edges incl. self loops
#define FIN  256
#define D1   512            // H1*C1
#define NEG  0.2f
#define CAP  64             // bucket capacity per node

typedef unsigned short ushort;
typedef __attribute__((ext_vector_type(8))) short   s16x8;
typedef __attribute__((ext_vector_type(4))) float   f32x4;
typedef __attribute__((ext_vector_type(4))) unsigned short u16x4;
typedef __attribute__((ext_vector_type(2))) unsigned short u16x2;

#define GL16(g,s) __builtin_amdgcn_global_load_lds((const __attribute__((address_space(1))) unsigned*)(g), (__attribute__((address_space(3))) unsigned*)(s), 16, 0, 0)

__device__ __forceinline__ float lrelu(float x){ return x > 0.f ? x : NEG*x; }
__device__ __forceinline__ float b2f(ushort u){ return __uint_as_float(((unsigned)u) << 16); }
__device__ __forceinline__ ushort f2bf(float f){
  unsigned u = __float_as_uint(f);
  return (ushort)((u + 0x7fffu + ((u >> 16) & 1u)) >> 16);
}
__device__ __forceinline__ float wsumf(float v){
#pragma unroll
  for (int o = 32; o > 0; o >>= 1) v += __shfl_xor(v, o);
  return v;
}

// ---------------- fused: zero cnt + PE zero-row + BN scale/shift ---------------
__global__ __launch_bounds__(1024) void zero_prep_kernel(int* __restrict__ cnt,
                            ushort* __restrict__ PE,
                            const float* __restrict__ g1, const float* __restrict__ be1,
                            const float* __restrict__ mu1, const float* __restrict__ va1,
                            const float* __restrict__ g2, const float* __restrict__ be2,
                            const float* __restrict__ mu2, const float* __restrict__ va2,
                            const float* __restrict__ b1,
                            float* __restrict__ sc1, float* __restrict__ sh1,
                            float* __restrict__ sc2, float* __restrict__ sh2)
{
  int i = blockIdx.x*1024 + threadIdx.x;
  if (i < NN) cnt[i] = 0;
  if (blockIdx.x == 0){
    int t = threadIdx.x;
    if (t < FIN){ float s = g1[t]*rsqrtf(va1[t]+1e-5f); sc1[t]=s; sh1[t]=be1[t]-mu1[t]*s; }
    if (t < D1){ float s = g2[t]*rsqrtf(va2[t]+1e-5f); sc2[t]=s; sh2[t]=be2[t]+(b1[t]-mu2[t])*s; }
    if (t < 64) PE[((size_t)NN << 6) + t] = 0;   // zero pad-row for agg2
  }
}

// ---------------- fused kernel 2: fill + K1T build (+k0) + c2/a2s ---------------
__global__ __launch_bounds__(256) void prep_all_kernel(
    const int* __restrict__ rows, const int* __restrict__ cols,
    int* __restrict__ cnt, int* __restrict__ cs,
    const float* __restrict__ W1, const float* __restrict__ W2,
    const float* __restrict__ sc1, const float* __restrict__ sh1,
    const float* __restrict__ sc2, const float* __restrict__ sh2,
    const float* __restrict__ att1, const float* __restrict__ att2,
    ushort* __restrict__ K1T, float* __restrict__ k0v,
    float* __restrict__ c2, float* __restrict__ a2s)
{
  int b = blockIdx.x;
  if (b < 1407){                        // ---- bucket fill ----
    int e = b*256 + threadIdx.x;
    if (e >= ET) return;
    int r, c;
    if (e < EE){ r = rows[e]; c = cols[e]; } else { r = e - EE; c = r; }
    int slot = atomicAdd(&cnt[r], 1);
    if (slot < CAP) cs[(r << 6) + slot] = c;
    return;
  }
  if (b < 1631){                        // ---- K1T row t ----
    __shared__ float wcol[128];
    __shared__ float red[4];
    int t = b - 1407;
    int k = threadIdx.x;
    float val = 0.f;
    if (t < 200){
      int h;
      if (t < 192){
        h = t & 3; int j = t >> 2;
        if (k < 128){ int kk = h*128 + k; wcol[k] = W2[(size_t)kk*48 + j] * sc2[kk]; }
      } else {
        h = (t - 192) & 3; int off = ((t - 192) >= 4) ? 128 : 0;
        if (k < 128) wcol[k] = att1[h*256 + off + k];
      }
      __syncthreads();
      const float* wr = W1 + (size_t)k*D1 + h*128;
#pragma unroll
      for (int kk = 0; kk < 128; kk += 4){
        float4 wv = *(const float4*)(wr + kk);
        float4 cv = *(const float4*)(wcol + kk);
        val += wv.x*cv.x + wv.y*cv.y + wv.z*cv.z + wv.w*cv.w;
      }
      K1T[(size_t)t*FIN + k] = f2bf(val * sc1[k]);
      float part = wsumf(sh1[k] * val);
      if ((k & 63) == 0) red[k >> 6] = part;
      __syncthreads();
      if (k == 0) k0v[t] = red[0] + red[1] + red[2] + red[3];
    } else {
      K1T[(size_t)t*FIN + k] = 0;
      if (k == 0) k0v[t] = 0.f;
    }
    return;
  }
  {                                     // ---- c2 + a2s (12 blocks) ----
    int bb = b - 1631;
    if (bb == 0 && threadIdx.x < 48){
      int h = threadIdx.x/6, c = threadIdx.x%6;
      a2s[threadIdx.x] = att2[h*12 + c] + att2[h*12 + 6 + c];
    }
    int w = bb*4 + (threadIdx.x >> 6);
    int lane = threadIdx.x & 63;
    if (w >= 48) return;
    float acc = 0.f;
    for (int k = lane; k < D1; k += 64) acc += sh2[k] * W2[(size_t)k*48 + w];
    acc = wsumf(acc);
    if (lane == 0) c2[w] = acc;
  }
}

// ---------------- unified GEMM: bf16(X) @ K1T^T + k0 -> Gs(sliced) + ai + aj ----
// Gs layout: slice s = j/6 owns j%6; row (s,n) = 64B: [6 jj][4 h] bf16 + 16B pad
__global__ __launch_bounds__(256) void gemmG_mfma(const float* __restrict__ X,
                                                  const ushort* __restrict__ K1T,
                                                  const float* __restrict__ k0v,
                                                  ushort* __restrict__ Gs,
                                                  float* __restrict__ ai,
                                                  float* __restrict__ aj)
{
  __shared__ ushort As[64*64];    // 8KB, XOR-swizzled
  __shared__ ushort Bs[224*64];   // 28KB
  int row0 = blockIdx.x * 64;
  int tid = threadIdx.x, lane = tid & 63, wave = tid >> 6;
  f32x4 acc[13] = {};
  int srow = lane >> 3;
  int scolb = (lane & 7) * 16;
#pragma unroll
  for (int kt = 0; kt < 4; ++kt){
    int k0 = kt*64;
#pragma unroll
    for (int j = 0; j < 2; ++j){
      int c = wave*2 + j;
      int rl = c*8 + srow;
      int rowg = row0 + rl; if (rowg >= NN) rowg = 0;
      int j0 = ((lane & 7) ^ (rl & 7)) * 8;
      const float* src = X + (size_t)rowg*FIN + k0 + j0;
      float4 v0 = *(const float4*)src;
      float4 v1 = *(const float4*)(src + 4);
      s16x8 o;
      o[0]=(short)f2bf(v0.x); o[1]=(short)f2bf(v0.y); o[2]=(short)f2bf(v0.z); o[3]=(short)f2bf(v0.w);
      o[4]=(short)f2bf(v1.x); o[5]=(short)f2bf(v1.y); o[6]=(short)f2bf(v1.z); o[7]=(short)f2bf(v1.w);
      *(s16x8*)((char*)As + c*1024 + lane*16) = o;
    }
#pragma unroll
    for (int j = 0; j < 7; ++j){
      int c = wave*7 + j;
      int row = c*8 + srow;
      int cb = scolb ^ ((row & 7) << 4);
      GL16((const char*)(K1T + (size_t)row*FIN + k0) + cb, (char*)Bs + c*1024);
    }
    __syncthreads();
#pragma unroll
    for (int kk = 0; kk < 2; ++kk){
      int kb = kk*64 + (lane >> 4)*16;
      int arow = wave*16 + (lane & 15);
      s16x8 a = *(const s16x8*)((const char*)As + arow*128 + (kb ^ ((arow & 7) << 4)));
#pragma unroll
      for (int ni = 0; ni < 13; ++ni){
        int row = ni*16 + (lane & 15);
        s16x8 bfrag = *(const s16x8*)((const char*)Bs + row*128 + (kb ^ ((row & 7) << 4)));
        acc[ni] = __builtin_amdgcn_mfma_f32_16x16x32_bf16(a, bfrag, acc[ni], 0, 0, 0);
      }
    }
    __syncthreads();
  }
  int cl = lane & 15;
#pragma unroll
  for (int ni = 0; ni < 12; ++ni){
    int t = ni*16 + cl;
    int j = t >> 2, h = t & 3;
    int s = j / 6, jj = j - s*6;
    float kc = k0v[t];
#pragma unroll
    for (int rr = 0; rr < 4; ++rr){
      int row = row0 + wave*16 + (lane >> 4)*4 + rr;
      Gs[((size_t)(s*NP + row))*32 + jj*4 + h] = f2bf(acc[ni][rr] + kc);
    }
  }
  if (cl < 8){
    float kc = k0v[192 + cl];
#pragma unroll
    for (int rr = 0; rr < 4; ++rr){
      int row = row0 + wave*16 + (lane >> 4)*4 + rr;
      float v = acc[12][rr] + kc;
      if (cl < 4) ai[(size_t)row*4 + cl] = v;
      else        aj[(size_t)row*4 + (cl-4)] = v;
    }
  }
}

// ---------------- dinv: per-node inverse softmax denominators (4 heads) ---------
__global__ __launch_bounds__(256) void dinv_kernel(const float* __restrict__ ai,
                                                   const float* __restrict__ aj,
                                                   const int* __restrict__ cnt,
                                                   const int* __restrict__ cs,
                                                   float* __restrict__ dinv)
{
  int lane = threadIdx.x & 63;
  int wave = threadIdx.x >> 6;
  int n0 = blockIdx.x*8 + wave*2, n1 = n0 + 1;
  int deg0 = cnt[n0]; deg0 = deg0 > CAP ? CAP : deg0;
  int deg1 = cnt[n1]; deg1 = deg1 > CAP ? CAP : deg1;
  float4 an0 = *(const float4*)(ai + (size_t)n0*4);
  float4 an1 = *(const float4*)(ai + (size_t)n1*4);
  float e00=0,e01=0,e02=0,e03=0, e10=0,e11=0,e12=0,e13=0;
  if (lane < deg0){
    int c = cs[(n0 << 6) + lane];
    float4 av = *(const float4*)(aj + (size_t)c*4);
    e00 = __expf(lrelu(an0.x+av.x)); e01 = __expf(lrelu(an0.y+av.y));
    e02 = __expf(lrelu(an0.z+av.z)); e03 = __expf(lrelu(an0.w+av.w));
  }
  if (lane < deg1){
    int c = cs[(n1 << 6) + lane];
    float4 av = *(const float4*)(aj + (size_t)c*4);
    e10 = __expf(lrelu(an1.x+av.x)); e11 = __expf(lrelu(an1.y+av.y));
    e12 = __expf(lrelu(an1.z+av.z)); e13 = __expf(lrelu(an1.w+av.w));
  }
  float d00 = wsumf(e00)+1e-16f, d01 = wsumf(e01)+1e-16f;
  float d02 = wsumf(e02)+1e-16f, d03 = wsumf(e03)+1e-16f;
  float d10 = wsumf(e10)+1e-16f, d11 = wsumf(e11)+1e-16f;
  float d12 = wsumf(e12)+1e-16f, d13 = wsumf(e13)+1e-16f;
  if (lane == 0){
    *(float4*)(dinv + (size_t)n0*4) = make_float4(1.f/d00, 1.f/d01, 1.f/d02, 1.f/d03);
    *(float4*)(dinv + (size_t)n1*4) = make_float4(1.f/d10, 1.f/d11, 1.f/d12, 1.f/d13);
  }
}

// ---------------- sliced layer-1 aggregation: h2g[n][j] partials ---------------
// block: slice = bid&7 (XCD-pinned), 8 nodes; wave: 2 nodes, 4 edges/iter/node-pair
__global__ __launch_bounds__(256) void aggS_kernel(const ushort* __restrict__ Gs,
                                                   const float* __restrict__ ai,
                                                   const float* __restrict__ aj,
                                                   const float* __restrict__ dinv,
                                                   const int* __restrict__ cnt,
                                                   const int* __restrict__ cs,
                                                   float* __restrict__ h2g)
{
  __shared__ int csh[4][2][64];
  int bid = blockIdx.x;
  int s = bid & 7;
  int grp = bid >> 3;
  int lane = threadIdx.x & 63;
  int wave = threadIdx.x >> 6;
  int n0 = grp*8 + wave*2, n1 = n0 + 1;
  int deg0 = cnt[n0]; deg0 = deg0 > CAP ? CAP : deg0;
  int deg1 = cnt[n1]; deg1 = deg1 > CAP ? CAP : deg1;
  csh[wave][0][lane] = (lane < deg0) ? cs[(n0 << 6) + lane] : 0;
  csh[wave][1][lane] = (lane < deg1) ? cs[(n1 << 6) + lane] : 0;
  int g = lane >> 4, l = lane & 15;
  int hp = l & 1;                       // 0 -> heads {0,1}, 1 -> heads {2,3}
  float4 an0 = *(const float4*)(ai + (size_t)n0*4);
  float4 an1 = *(const float4*)(ai + (size_t)n1*4);
  float4 dv0 = *(const float4*)(dinv + (size_t)n0*4);
  float4 dv1 = *(const float4*)(dinv + (size_t)n1*4);
  float ai0a = hp ? an0.z : an0.x, ai0b = hp ? an0.w : an0.y;
  float ai1a = hp ? an1.z : an1.x, ai1b = hp ? an1.w : an1.y;
  float di0a = hp ? dv0.z : dv0.x, di0b = hp ? dv0.w : dv0.y;
  float di1a = hp ? dv1.z : dv1.x, di1b = hp ? dv1.w : dv1.y;
  int lidx = (l < 12) ? l : 0;
  const ushort* Gb = Gs + (size_t)s*NP*32 + lidx*2;
  const float* ajb = aj + hp*2;
  float A0a=0.f, A0b=0.f, A1a=0.f, A1b=0.f;
  int dm = deg0 > deg1 ? deg0 : deg1;
  for (int e = 0; e < dm; e += 4){
    int e0 = e + g;                     // <= 63
    int c0 = csh[wave][0][e0];
    int c1 = csh[wave][1][e0];
    float2 aj0 = *(const float2*)(ajb + (size_t)c0*4);
    float2 aj1 = *(const float2*)(ajb + (size_t)c1*4);
    u16x2 g0 = *(const u16x2*)(Gb + (size_t)c0*32);
    u16x2 g1 = *(const u16x2*)(Gb + (size_t)c1*32);
    float w0a = __expf(lrelu(ai0a + aj0.x)) * di0a;
    float w0b = __expf(lrelu(ai0b + aj0.y)) * di0b;
    float w1a = __expf(lrelu(ai1a + aj1.x)) * di1a;
    float w1b = __expf(lrelu(ai1b + aj1.y)) * di1b;
    bool a0 = e0 < deg0, a1 = e0 < deg1;
    w0a = a0 ? w0a : 0.f; w0b = a0 ? w0b : 0.f;
    w1a = a1 ? w1a : 0.f; w1b = a1 ? w1b : 0.f;
    A0a += w0a * b2f(g0[0]); A0b += w0b * b2f(g0[1]);
    A1a += w1a * b2f(g1[0]); A1b += w1b * b2f(g1[1]);
  }
  // reduce across the 4 edge-groups (same l, lanes xor 16/32)
  A0a += __shfl_xor(A0a, 16); A0a += __shfl_xor(A0a, 32);
  A0b += __shfl_xor(A0b, 16); A0b += __shfl_xor(A0b, 32);
  A1a += __shfl_xor(A1a, 16); A1a += __shfl_xor(A1a, 32);
  A1b += __shfl_xor(A1b, 16); A1b += __shfl_xor(A1b, 32);
  float p0 = A0a + A0b;                 // lane l: values v=2l, 2l+1
  float p1 = A1a + A1b;
  float t0 = p0 + __shfl_xor(p0, 1);    // combine l, l^1 -> h-sum of jj = l>>1
  float t1 = p1 + __shfl_xor(p1, 1);
  if (lane < 12 && !(lane & 1)){
    h2g[(size_t)n0*48 + s*6 + (lane >> 1)] = t0;
    h2g[(size_t)n1*48 + s*6 + (lane >> 1)] = t1;
  }
}

// ---------------- PE finalize: h2 -> tanh/eh -> PE rows ------------------------
__global__ __launch_bounds__(256) void pe_kernel(const float* __restrict__ h2g,
                                                 const float* __restrict__ c2,
                                                 const float* __restrict__ a2s,
                                                 ushort* __restrict__ PE)
{
  int lane = threadIdx.x & 63;
  int wave = threadIdx.x >> 6;
  int n0 = blockIdx.x*8 + wave*2, n1 = n0 + 1;
  bool aclane = lane < 48;
  int lidx = aclane ? lane : 0;
  float cc2 = aclane ? c2[lidx] : 0.f;
  float aa2 = aclane ? a2s[lidx] : 0.f;
  float h0 = (aclane ? h2g[(size_t)n0*48 + lidx] : 0.f) + cc2;
  float h1_ = (aclane ? h2g[(size_t)n1*48 + lidx] : 0.f) + cc2;
  float s0 = h0*aa2, s1 = h1_*aa2;
  float t0 = 0.f, t1 = 0.f;
  int base = (lane/6)*6;
#pragma unroll
  for (int i = 0; i < 6; ++i){ t0 += __shfl(s0, base + i); t1 += __shfl(s1, base + i); }
  if (aclane){
    float eh0 = __expf(tanhf(t0));
    float eh1 = __expf(tanhf(t1));
    ushort* pe0 = PE + ((size_t)n0 << 6);
    ushort* pe1 = PE + ((size_t)n1 << 6);
    pe0[lane] = f2bf(eh0*h0);
    pe1[lane] = f2bf(eh1*h1_);
    if ((lane % 6) == 0){ pe0[48 + lane/6] = f2bf(eh0); pe1[48 + lane/6] = f2bf(eh1); }
  }
}

// ---------------- layer-2 agg: 2 nodes per wave, zero-row padded ----------------
__global__ __launch_bounds__(256) void agg2_kernel(const ushort* __restrict__ PE,
                                                   const int* __restrict__ cnt,
                                                   const int* __restrict__ cs,
                                                   const float* __restrict__ bias2,
                                                   float* __restrict__ out)
{
  __shared__ int csh[4][2][64];     // byte offsets c*128 (pad -> zero row NN)
  int lane = threadIdx.x & 63;
  int wave = threadIdx.x >> 6;
  int n0 = blockIdx.x*8 + wave*2;
  int n1 = n0 + 1;
  int deg0 = cnt[n0]; deg0 = deg0 > CAP ? CAP : deg0;
  int deg1 = cnt[n1]; deg1 = deg1 > CAP ? CAP : deg1;
  int lidx = (lane < 56) ? lane : 0;
  const char* PEb = (const char*)PE + (size_t)lidx*2;
  const int ZOFF = NN << 7;
  csh[wave][0][lane] = (lane < deg0) ? (cs[(n0 << 6) + lane] << 7) : ZOFF;
  csh[wave][1][lane] = (lane < deg1) ? (cs[(n1 << 6) + lane] << 7) : ZOFF;
  float acc0 = 0.f, acc1 = 0.f;
  int dm = deg0 > deg1 ? deg0 : deg1;
  for (int e = 0; e < dm; e += 2){
    int o00 = csh[wave][0][e], o01 = csh[wave][0][e+1];
    int o10 = csh[wave][1][e], o11 = csh[wave][1][e+1];
    float v00 = b2f(*(const ushort*)(PEb + o00));
    float v01 = b2f(*(const ushort*)(PEb + o01));
    float v10 = b2f(*(const ushort*)(PEb + o10));
    float v11 = b2f(*(const ushort*)(PEb + o11));
    acc0 += v00 + v01;
    acc1 += v10 + v11;
  }

  int hh = (lane < 48) ? lane/6 : 0;
  float den0 = __shfl(acc0, 48 + hh);
  float den1 = __shfl(acc1, 48 + hh);
  float v0 = acc0 / den0, v1 = acc1 / den1;
  int cc = lane % 6;
  float s0 = 0.f, s1 = 0.f;
#pragma unroll
  for (int qq = 0; qq < 8; ++qq){ s0 += __shfl(v0, cc + 6*qq); s1 += __shfl(v1, cc + 6*qq); }
  float bb = bias2[cc];
  float u0 = s0*(1.f/8.f) + bb;
  float u1 = s1*(1.f/8.f) + bb;
  u0 = u0 > 0.f ? u0 : (__expf(u0) - 1.f);
  u1 = u1 > 0.f ? u1 : (__expf(u1) - 1.f);
  float val0 = (lane < 6) ? u0 : -1e30f;
  float val1 = (lane < 6) ? u1 : -1e30f;
  float mx0 = val0, mx1 = val1;
#pragma unroll
  for (int o = 1; o < 8; o <<= 1){ mx0 = fmaxf(mx0, __shfl_xor(mx0, o)); mx1 = fmaxf(mx1, __shfl_xor(mx1, o)); }
  float ex0 = (lane < 6) ? __expf(val0 - mx0) : 0.f;
  float ex1 = (lane < 6) ? __expf(val1 - mx1) : 0.f;
#pragma unroll
  for (int o = 1; o < 8; o <<= 1){ ex0 += __shfl_xor(ex0, o); ex1 += __shfl_xor(ex1, o); }
  if (lane < 6){
    out[(size_t)n0*6 + lane] = val0 - mx0 - __logf(ex0);
    out[(size_t)n1*6 + lane] = val1 - mx1 - __logf(ex1);
  }
}

// ---------------- launch ---------------------------------------------------------
extern "C" void kernel_launch(void* const* d_in, const int* in_sizes, int n_in,
                              void* d_out, int out_size, void* d_ws, size_t ws_size,
                              hipStream_t stream)
{
  (void)in_sizes; (void)n_in; (void)out_size; (void)ws_size;
  const float* x   = (const float*)d_in[0];
  const int*   ei  = (const int*)  d_in[1];
  const float* g1  = (const float*)d_in[2];
  const float* be1 = (const float*)d_in[3];
  const float* mu1 = (const float*)d_in[4];
  const float* va1 = (const float*)d_in[5];
  const float* W1  = (const float*)d_in[6];
  const float* at1 = (const float*)d_in[7];
  const float* b1  = (const float*)d_in[8];
  const float* g2  = (const float*)d_in[9];
  const float* be2 = (const float*)d_in[10];
  const float* mu2 = (const float*)d_in[11];
  const float* va2 = (const float*)d_in[12];
  const float* W2  = (const float*)d_in[13];
  const float* at2 = (const float*)d_in[14];
  const float* b2  = (const float*)d_in[15];
  const int* rows = ei;
  const int* cols = ei + EE;
  float* out = (float*)d_out;

  char* p = (char*)d_ws;
  auto carve = [&](size_t bytes)->void*{ void* r = (void*)p; p += (bytes + 255) & ~(size_t)255; return r; };
  ushort* K1T = (ushort*)carve((size_t)224*FIN*2);
  ushort* Gs  = (ushort*)carve((size_t)8*NP*32*2);    // 8 slices x [NP] x 64B rows
  ushort* PE  = (ushort*)carve((size_t)(NN+1)*64*2);  // [NN+1][64] bf16 (row NN = zeros)
  float* h2g  = (float*)carve((size_t)NN*48*4);
  float* dinv = (float*)carve((size_t)NN*4*4);
  float* k0v  = (float*)carve(224*4);
  float* c2   = (float*)carve(48*4);
  float* a2s  = (float*)carve(48*4);
  float* ai   = (float*)carve((size_t)NP*4*4);
  float* aj   = (float*)carve((size_t)NP*4*4);
  float* sc1  = (float*)carve(FIN*4);
  float* sh1  = (float*)carve(FIN*4);
  float* sc2  = (float*)carve(D1*4);
  float* sh2  = (float*)carve(D1*4);
  int* cnt    = (int*)carve((size_t)NN*4);
  int* cs     = (int*)carve((size_t)NN*CAP*4);

  zero_prep_kernel<<<40, 1024, 0, stream>>>(cnt, PE, g1,be1,mu1,va1,g2,be2,mu2,va2,b1,
                                            sc1,sh1,sc2,sh2);
  prep_all_kernel<<<1643, 256, 0, stream>>>(rows, cols, cnt, cs,
                                            W1, W2, sc1, sh1, sc2, sh2, at1, at2,
                                            K1T, k0v, c2, a2s);
  gemmG_mfma<<<626, 256, 0, stream>>>(x, K1T, k0v, Gs, ai, aj);
  dinv_kernel<<<NN/8, 256, 0, stream>>>(ai, aj, cnt, cs, dinv);
  aggS_kernel<<<NN, 256, 0, stream>>>(Gs, ai, aj, dinv, cnt, cs, h2g);
  pe_kernel<<<NN/8, 256, 0, stream>>>(h2g, c2, a2s, PE);
  agg2_kernel<<<NN/8, 256, 0, stream>>>(PE, cnt, cs, b2, out);
}

// Round 15
// 97.892 us; speedup vs baseline: 1.6022x; 1.6022x over previous
//
#include <hip/hip_runtime.h>
#include <math.h>

#define NN   40000
#define NP   40064          // padded rows (multiple of 64)
#define EE   320000
#define ET   (EE + NN)      // 360000 edges incl. self loops
#define FIN  256
#define D1   512            // H1*C1
#define NEG  0.2f
#define CAP  64             // bucket capacity per node

typedef unsigned short ushort;
typedef __attribute__((ext_vector_type(8))) short   s16x8;
typedef __attribute__((ext_vector_type(4))) float   f32x4;
typedef __attribute__((ext_vector_type(4))) unsigned short u16x4;

#define GL16(g,s) __builtin_amdgcn_global_load_lds((const __attribute__((address_space(1))) unsigned*)(g), (__attribute__((address_space(3))) unsigned*)(s), 16, 0, 0)

__device__ __forceinline__ float lrelu(float x){ return x > 0.f ? x : NEG*x; }
__device__ __forceinline__ float b2f(ushort u){ return __uint_as_float(((unsigned)u) << 16); }
__device__ __forceinline__ ushort f2bf(float f){
  unsigned u = __float_as_uint(f);
  return (ushort)((u + 0x7fffu + ((u >> 16) & 1u)) >> 16);
}
__device__ __forceinline__ float wsumf(float v){
#pragma unroll
  for (int o = 32; o > 0; o >>= 1) v += __shfl_xor(v, o);
  return v;
}

// ---------------- fused: zero cnt + PE zero-row + BN scale/shift ---------------
__global__ __launch_bounds__(1024) void zero_prep_kernel(int* __restrict__ cnt,
                            ushort* __restrict__ PE,
                            const float* __restrict__ g1, const float* __restrict__ be1,
                            const float* __restrict__ mu1, const float* __restrict__ va1,
                            const float* __restrict__ g2, const float* __restrict__ be2,
                            const float* __restrict__ mu2, const float* __restrict__ va2,
                            const float* __restrict__ b1,
                            float* __restrict__ sc1, float* __restrict__ sh1,
                            float* __restrict__ sc2, float* __restrict__ sh2)
{
  int i = blockIdx.x*1024 + threadIdx.x;
  if (i < NN) cnt[i] = 0;
  if (blockIdx.x == 0){
    int t = threadIdx.x;
    if (t < FIN){ float s = g1[t]*rsqrtf(va1[t]+1e-5f); sc1[t]=s; sh1[t]=be1[t]-mu1[t]*s; }
    if (t < D1){ float s = g2[t]*rsqrtf(va2[t]+1e-5f); sc2[t]=s; sh2[t]=be2[t]+(b1[t]-mu2[t])*s; }
    if (t < 64) PE[((size_t)NN << 6) + t] = 0;   // zero pad-row for agg2
  }
}

// ---------------- fused kernel 2: fill + K1T build (+k0) + c2/a2s ---------------
__global__ __launch_bounds__(256) void prep_all_kernel(
    const int* __restrict__ rows, const int* __restrict__ cols,
    int* __restrict__ cnt, int* __restrict__ cs,
    const float* __restrict__ W1, const float* __restrict__ W2,
    const float* __restrict__ sc1, const float* __restrict__ sh1,
    const float* __restrict__ sc2, const float* __restrict__ sh2,
    const float* __restrict__ att1, const float* __restrict__ att2,
    ushort* __restrict__ K1T, float* __restrict__ k0v,
    float* __restrict__ c2, float* __restrict__ a2s)
{
  int b = blockIdx.x;
  if (b < 1407){                        // ---- bucket fill ----
    int e = b*256 + threadIdx.x;
    if (e >= ET) return;
    int r, c;
    if (e < EE){ r = rows[e]; c = cols[e]; } else { r = e - EE; c = r; }
    int slot = atomicAdd(&cnt[r], 1);
    if (slot < CAP) cs[(r << 6) + slot] = c;
    return;
  }
  if (b < 1631){                        // ---- K1T row t ----
    __shared__ float wcol[128];
    __shared__ float red[4];
    int t = b - 1407;
    int k = threadIdx.x;
    float val = 0.f;
    if (t < 200){
      int h;
      if (t < 192){
        h = t & 3; int j = t >> 2;
        if (k < 128){ int kk = h*128 + k; wcol[k] = W2[(size_t)kk*48 + j] * sc2[kk]; }
      } else {
        h = (t - 192) & 3; int off = ((t - 192) >= 4) ? 128 : 0;
        if (k < 128) wcol[k] = att1[h*256 + off + k];
      }
      __syncthreads();
      const float* wr = W1 + (size_t)k*D1 + h*128;
#pragma unroll
      for (int kk = 0; kk < 128; kk += 4){
        float4 wv = *(const float4*)(wr + kk);
        float4 cv = *(const float4*)(wcol + kk);
        val += wv.x*cv.x + wv.y*cv.y + wv.z*cv.z + wv.w*cv.w;
      }
      K1T[(size_t)t*FIN + k] = f2bf(val * sc1[k]);
      float part = wsumf(sh1[k] * val);
      if ((k & 63) == 0) red[k >> 6] = part;
      __syncthreads();
      if (k == 0) k0v[t] = red[0] + red[1] + red[2] + red[3];
    } else {
      K1T[(size_t)t*FIN + k] = 0;
      if (k == 0) k0v[t] = 0.f;
    }
    return;
  }
  {                                     // ---- c2 + a2s (12 blocks) ----
    int bb = b - 1631;
    if (bb == 0 && threadIdx.x < 48){
      int h = threadIdx.x/6, c = threadIdx.x%6;
      a2s[threadIdx.x] = att2[h*12 + c] + att2[h*12 + 6 + c];
    }
    int w = bb*4 + (threadIdx.x >> 6);
    int lane = threadIdx.x & 63;
    if (w >= 48) return;
    float acc = 0.f;
    for (int k = lane; k < D1; k += 64) acc += sh2[k] * W2[(size_t)k*48 + w];
    acc = wsumf(acc);
    if (lane == 0) c2[w] = acc;
  }
}

// ---------------- unified GEMM: bf16(X) @ K1T^T + k0 -> G + ai + aj -------------
__global__ __launch_bounds__(256) void gemmG_mfma(const float* __restrict__ X,
                                                  const ushort* __restrict__ K1T,
                                                  const float* __restrict__ k0v,
                                                  ushort* __restrict__ G,
                                                  float* __restrict__ ai,
                                                  float* __restrict__ aj)
{
  __shared__ ushort As[64*64];    // 8KB, XOR-swizzled
  __shared__ ushort Bs[224*64];   // 28KB
  int row0 = blockIdx.x * 64;
  int tid = threadIdx.x, lane = tid & 63, wave = tid >> 6;
  f32x4 acc[13] = {};
  int srow = lane >> 3;
  int scolb = (lane & 7) * 16;
#pragma unroll
  for (int kt = 0; kt < 4; ++kt){
    int k0 = kt*64;
#pragma unroll
    for (int j = 0; j < 2; ++j){
      int c = wave*2 + j;
      int rl = c*8 + srow;
      int rowg = row0 + rl; if (rowg >= NN) rowg = 0;
      int j0 = ((lane & 7) ^ (rl & 7)) * 8;
      const float* src = X + (size_t)rowg*FIN + k0 + j0;
      float4 v0 = *(const float4*)src;
      float4 v1 = *(const float4*)(src + 4);
      s16x8 o;
      o[0]=(short)f2bf(v0.x); o[1]=(short)f2bf(v0.y); o[2]=(short)f2bf(v0.z); o[3]=(short)f2bf(v0.w);
      o[4]=(short)f2bf(v1.x); o[5]=(short)f2bf(v1.y); o[6]=(short)f2bf(v1.z); o[7]=(short)f2bf(v1.w);
      *(s16x8*)((char*)As + c*1024 + lane*16) = o;
    }
#pragma unroll
    for (int j = 0; j < 7; ++j){
      int c = wave*7 + j;
      int row = c*8 + srow;
      int cb = scolb ^ ((row & 7) << 4);
      GL16((const char*)(K1T + (size_t)row*FIN + k0) + cb, (char*)Bs + c*1024);
    }
    __syncthreads();
#pragma unroll
    for (int kk = 0; kk < 2; ++kk){
      int kb = kk*64 + (lane >> 4)*16;
      int arow = wave*16 + (lane & 15);
      s16x8 a = *(const s16x8*)((const char*)As + arow*128 + (kb ^ ((arow & 7) << 4)));
#pragma unroll
      for (int ni = 0; ni < 13; ++ni){
        int row = ni*16 + (lane & 15);
        s16x8 bfrag = *(const s16x8*)((const char*)Bs + row*128 + (kb ^ ((row & 7) << 4)));
        acc[ni] = __builtin_amdgcn_mfma_f32_16x16x32_bf16(a, bfrag, acc[ni], 0, 0, 0);
      }
    }
    __syncthreads();
  }
  int cl = lane & 15;
#pragma unroll
  for (int ni = 0; ni < 12; ++ni){
    int t = ni*16 + cl;
    float kc = k0v[t];
#pragma unroll
    for (int rr = 0; rr < 4; ++rr){
      int row = row0 + wave*16 + (lane >> 4)*4 + rr;
      G[(size_t)row*192 + t] = f2bf(acc[ni][rr] + kc);
    }
  }
  if (cl < 8){
    float kc = k0v[192 + cl];
#pragma unroll
    for (int rr = 0; rr < 4; ++rr){
      int row = row0 + wave*16 + (lane >> 4)*4 + rr;
      float v = acc[12][rr] + kc;
      if (cl < 4) ai[(size_t)row*4 + cl] = v;
      else        aj[(size_t)row*4 + (cl-4)] = v;
    }
  }
}

// ---------------- fused layer-1 agg + h2 + PE: 2 nodes per wave -----------------
// no max-subtraction (logits bounded), deferred normalization (divide at end)
__global__ __launch_bounds__(256) void aggA_kernel(const ushort* __restrict__ G,
                                                   const float* __restrict__ ai,
                                                   const float* __restrict__ aj,
                                                   const int* __restrict__ cnt,
                                                   const int* __restrict__ cs,
                                                   const float* __restrict__ c2,
                                                   const float* __restrict__ a2s,
                                                   ushort* __restrict__ PE)
{
  __shared__ float wsh[4][2][64][4];
  __shared__ int   csh[4][2][64];     // byte offsets c*384 (0 when inactive, weight 0)
  int lane = threadIdx.x & 63;
  int wave = threadIdx.x >> 6;
  int n0 = blockIdx.x*8 + wave*2;
  int n1 = n0 + 1;
  int deg0 = cnt[n0]; deg0 = deg0 > CAP ? CAP : deg0;
  int deg1 = cnt[n1]; deg1 = deg1 > CAP ? CAP : deg1;
  float4 an0 = *(const float4*)(ai + (size_t)n0*4);
  float4 an1 = *(const float4*)(ai + (size_t)n1*4);
  bool aclane = lane < 48;
  int lidx = aclane ? lane : 0;
  const char* Gb = (const char*)G + (size_t)lidx*8;

  // ---- weight phase, both nodes (raw exp, no max-sub) ----
  bool a0 = lane < deg0, a1 = lane < deg1;
  int c0 = 0, c1 = 0;
  float e00=0,e01=0,e02=0,e03=0, e10=0,e11=0,e12=0,e13=0;
  if (a0){
    c0 = cs[(n0 << 6) + lane];
    float4 av = *(const float4*)(aj + (size_t)c0*4);
    e00 = __expf(lrelu(an0.x+av.x)); e01 = __expf(lrelu(an0.y+av.y));
    e02 = __expf(lrelu(an0.z+av.z)); e03 = __expf(lrelu(an0.w+av.w));
  }
  if (a1){
    c1 = cs[(n1 << 6) + lane];
    float4 av = *(const float4*)(aj + (size_t)c1*4);
    e10 = __expf(lrelu(an1.x+av.x)); e11 = __expf(lrelu(an1.y+av.y));
    e12 = __expf(lrelu(an1.z+av.z)); e13 = __expf(lrelu(an1.w+av.w));
  }
  float d00 = wsumf(e00)+1e-16f, d01 = wsumf(e01)+1e-16f;
  float d02 = wsumf(e02)+1e-16f, d03 = wsumf(e03)+1e-16f;
  float d10 = wsumf(e10)+1e-16f, d11 = wsumf(e11)+1e-16f;
  float d12 = wsumf(e12)+1e-16f, d13 = wsumf(e13)+1e-16f;
  wsh[wave][0][lane][0]=e00; wsh[wave][0][lane][1]=e01;
  wsh[wave][0][lane][2]=e02; wsh[wave][0][lane][3]=e03;
  wsh[wave][1][lane][0]=e10; wsh[wave][1][lane][1]=e11;
  wsh[wave][1][lane][2]=e12; wsh[wave][1][lane][3]=e13;
  csh[wave][0][lane] = a0 ? c0*384 : 0;
  csh[wave][1][lane] = a1 ? c1*384 : 0;

  // ---- gather, both nodes interleaved (4 independent loads/iter) ----
  float A00=0,A01=0,A02=0,A03=0, A10=0,A11=0,A12=0,A13=0;
  int dm = deg0 > deg1 ? deg0 : deg1;
  for (int e = 0; e < dm; e += 2){          // e even, e+1 <= 63
    int o00 = csh[wave][0][e], o01 = csh[wave][0][e+1];
    int o10 = csh[wave][1][e], o11 = csh[wave][1][e+1];
    u16x4 v00 = *(const u16x4*)(Gb + o00);
    u16x4 v01 = *(const u16x4*)(Gb + o01);
    u16x4 v10 = *(const u16x4*)(Gb + o10);
    u16x4 v11 = *(const u16x4*)(Gb + o11);
    float4 w00 = *(const float4*)wsh[wave][0][e];
    float4 w01 = *(const float4*)wsh[wave][0][e+1];
    float4 w10 = *(const float4*)wsh[wave][1][e];
    float4 w11 = *(const float4*)wsh[wave][1][e+1];
    A00 += w00.x*b2f(v00[0]) + w01.x*b2f(v01[0]);
    A01 += w00.y*b2f(v00[1]) + w01.y*b2f(v01[1]);
    A02 += w00.z*b2f(v00[2]) + w01.z*b2f(v01[2]);
    A03 += w00.w*b2f(v00[3]) + w01.w*b2f(v01[3]);
    A10 += w10.x*b2f(v10[0]) + w11.x*b2f(v11[0]);
    A11 += w10.y*b2f(v10[1]) + w11.y*b2f(v11[1]);
    A12 += w10.z*b2f(v10[2]) + w11.z*b2f(v11[2]);
    A13 += w10.w*b2f(v10[3]) + w11.w*b2f(v11[3]);
  }

  // ---- epilogue: normalize, h2, tanh-head sums, eh, PE writes ----
  float cc2 = aclane ? c2[lidx] : 0.f;
  float aa2 = aclane ? a2s[lidx] : 0.f;
  float h0 = A00/d00 + A01/d01 + A02/d02 + A03/d03 + cc2;
  float h1_ = A10/d10 + A11/d11 + A12/d12 + A13/d13 + cc2;
  float s0 = h0*aa2, s1 = h1_*aa2;
  float t0 = 0.f, t1 = 0.f;
  int base = (lane/6)*6;
#pragma unroll
  for (int i = 0; i < 6; ++i){ t0 += __shfl(s0, base + i); t1 += __shfl(s1, base + i); }
  if (aclane){
    float eh0 = __expf(tanhf(t0));
    float eh1 = __expf(tanhf(t1));
    ushort* pe0 = PE + ((size_t)n0 << 6);
    ushort* pe1 = PE + ((size_t)n1 << 6);
    pe0[lane] = f2bf(eh0*h0);
    pe1[lane] = f2bf(eh1*h1_);
    if ((lane % 6) == 0){ pe0[48 + lane/6] = f2bf(eh0); pe1[48 + lane/6] = f2bf(eh1); }
  }
}

// ---------------- layer-2 agg: 2 nodes per wave, zero-row padded ----------------
__global__ __launch_bounds__(256) void agg2_kernel(const ushort* __restrict__ PE,
                                                   const int* __restrict__ cnt,
                                                   const int* __restrict__ cs,
                                                   const float* __restrict__ bias2,
                                                   float* __restrict__ out)
{
  __shared__ int csh[4][2][64];     // byte offsets c*128 (pad -> zero row NN)
  int lane = threadIdx.x & 63;
  int wave = threadIdx.x >> 6;
  int n0 = blockIdx.x*8 + wave*2;
  int n1 = n0 + 1;
  int deg0 = cnt[n0]; deg0 = deg0 > CAP ? CAP : deg0;
  int deg1 = cnt[n1]; deg1 = deg1 > CAP ? CAP : deg1;
  int lidx = (lane < 56) ? lane : 0;
  const char* PEb = (const char*)PE + (size_t)lidx*2;
  const int ZOFF = NN << 7;
  csh[wave][0][lane] = (lane < deg0) ? (cs[(n0 << 6) + lane] << 7) : ZOFF;
  csh[wave][1][lane] = (lane < deg1) ? (cs[(n1 << 6) + lane] << 7) : ZOFF;
  float acc0 = 0.f, acc1 = 0.f;
  int dm = deg0 > deg1 ? deg0 : deg1;
  for (int e = 0; e < dm; e += 2){
    int o00 = csh[wave][0][e], o01 = csh[wave][0][e+1];
    int o10 = csh[wave][1][e], o11 = csh[wave][1][e+1];
    float v00 = b2f(*(const ushort*)(PEb + o00));
    float v01 = b2f(*(const ushort*)(PEb + o01));
    float v10 = b2f(*(const ushort*)(PEb + o10));
    float v11 = b2f(*(const ushort*)(PEb + o11));
    acc0 += v00 + v01;
    acc1 += v10 + v11;
  }

  int hh = (lane < 48) ? lane/6 : 0;
  float den0 = __shfl(acc0, 48 + hh);
  float den1 = __shfl(acc1, 48 + hh);
  float v0 = acc0 / den0, v1 = acc1 / den1;
  int cc = lane % 6;
  float s0 = 0.f, s1 = 0.f;
#pragma unroll
  for (int qq = 0; qq < 8; ++qq){ s0 += __shfl(v0, cc + 6*qq); s1 += __shfl(v1, cc + 6*qq); }
  float bb = bias2[cc];
  float u0 = s0*(1.f/8.f) + bb;
  float u1 = s1*(1.f/8.f) + bb;
  u0 = u0 > 0.f ? u0 : (__expf(u0) - 1.f);
  u1 = u1 > 0.f ? u1 : (__expf(u1) - 1.f);
  float val0 = (lane < 6) ? u0 : -1e30f;
  float val1 = (lane < 6) ? u1 : -1e30f;
  float mx0 = val0, mx1 = val1;
#pragma unroll
  for (int o = 1; o < 8; o <<= 1){ mx0 = fmaxf(mx0, __shfl_xor(mx0, o)); mx1 = fmaxf(mx1, __shfl_xor(mx1, o)); }
  float ex0 = (lane < 6) ? __expf(val0 - mx0) : 0.f;
  float ex1 = (lane < 6) ? __expf(val1 - mx1) : 0.f;
#pragma unroll
  for (int o = 1; o < 8; o <<= 1){ ex0 += __shfl_xor(ex0, o); ex1 += __shfl_xor(ex1, o); }
  if (lane < 6){
    out[(size_t)n0*6 + lane] = val0 - mx0 - __logf(ex0);
    out[(size_t)n1*6 + lane] = val1 - mx1 - __logf(ex1);
  }
}

// ---------------- launch ---------------------------------------------------------
extern "C" void kernel_launch(void* const* d_in, const int* in_sizes, int n_in,
                              void* d_out, int out_size, void* d_ws, size_t ws_size,
                              hipStream_t stream)
{
  (void)in_sizes; (void)n_in; (void)out_size; (void)ws_size;
  const float* x   = (const float*)d_in[0];
  const int*   ei  = (const int*)  d_in[1];
  const float* g1  = (const float*)d_in[2];
  const float* be1 = (const float*)d_in[3];
  const float* mu1 = (const float*)d_in[4];
  const float* va1 = (const float*)d_in[5];
  const float* W1  = (const float*)d_in[6];
  const float* at1 = (const float*)d_in[7];
  const float* b1  = (const float*)d_in[8];
  const float* g2  = (const float*)d_in[9];
  const float* be2 = (const float*)d_in[10];
  const float* mu2 = (const float*)d_in[11];
  const float* va2 = (const float*)d_in[12];
  const float* W2  = (const float*)d_in[13];
  const float* at2 = (const float*)d_in[14];
  const float* b2  = (const float*)d_in[15];
  const int* rows = ei;
  const int* cols = ei + EE;
  float* out = (float*)d_out;

  char* p = (char*)d_ws;
  auto carve = [&](size_t bytes)->void*{ void* r = (void*)p; p += (bytes + 255) & ~(size_t)255; return r; };
  ushort* K1T = (ushort*)carve((size_t)224*FIN*2);
  ushort* G   = (ushort*)carve((size_t)NP*192*2);     // [NP][192] bf16 (t = j*4+h)
  ushort* PE  = (ushort*)carve((size_t)(NN+1)*64*2);  // [NN+1][64] bf16 (row NN = zeros)
  float* k0v  = (float*)carve(224*4);
  float* c2   = (float*)carve(48*4);
  float* a2s  = (float*)carve(48*4);
  float* ai   = (float*)carve((size_t)NP*4*4);
  float* aj   = (float*)carve((size_t)NP*4*4);
  float* sc1  = (float*)carve(FIN*4);
  float* sh1  = (float*)carve(FIN*4);
  float* sc2  = (float*)carve(D1*4);
  float* sh2  = (float*)carve(D1*4);
  int* cnt    = (int*)carve((size_t)NN*4);
  int* cs     = (int*)carve((size_t)NN*CAP*4);

  zero_prep_kernel<<<40, 1024, 0, stream>>>(cnt, PE, g1,be1,mu1,va1,g2,be2,mu2,va2,b1,
                                            sc1,sh1,sc2,sh2);
  prep_all_kernel<<<1643, 256, 0, stream>>>(rows, cols, cnt, cs,
                                            W1, W2, sc1, sh1, sc2, sh2, at1, at2,
                                            K1T, k0v, c2, a2s);
  gemmG_mfma<<<626, 256, 0, stream>>>(x, K1T, k0v, G, ai, aj);
  aggA_kernel<<<NN/8, 256, 0, stream>>>(G, ai, aj, cnt, cs, c2, a2s, PE);
  agg2_kernel<<<NN/8, 256, 0, stream>>>(PE, cnt, cs, b2, out);
}